// Round 9
// baseline (6994.423 us; speedup 1.0000x reference)
//
#include <hip/hip_runtime.h>
#include <stdint.h>
#include <math.h>

// ---------------------------------------------------------------------------
// StoryJudger2: word branch (2x LSTM H=1000) + paragraph branch (2x biLSTM)
// B=8, S=256, V=50257, E=512, P=768, H=1000.
//
// Strategy (R4 scan structure + bounded-downside L2 fast path):
//  - Input projections xg = A @ Wih^T + b as bf16 MFMA GEMMs (f32 out).
//  - Recurrent scans: persistent kernel, 32 WGs x 512 thr per LSTM, work
//    self-assigned by PHYSICAL XCD (s_getreg HW_REG_XCC_ID + grid barrier +
//    spill list -> correct under any placement). Whh register-resident as
//    MFMA B-fragments. NO barrier: h stored BIT-INVERTED, dual store
//    (agent-scope sc0sc1 -> L3 truth, THEN plain store -> refresh local-L2
//    line for same-XCD readers; identical bytes => coherent under any
//    interleaving). Consumers poll each 8B granule: sc0 (local L2) probe
//    first, then sc0 sc1 (L3) for still-pending -> worst case == R4's pure
//    L3 polling. 0x0000 == not-written (|h|<1 never inverts to 0; slots
//    pre-zeroed). One __syncthreads per step (double-buffered LDS h tile).
//  - h buffers hold INVERTED bf16 -> kdecode before layer-1 GEMMs; kfinal
//    decodes inline.
//  - para reverse layer-1 only needs step 0 (h0=c0=0) -> closed form in final.
// ---------------------------------------------------------------------------

typedef __attribute__((ext_vector_type(8))) short short8;
typedef __attribute__((ext_vector_type(4))) float f32x4;
typedef __attribute__((ext_vector_type(4))) unsigned int u32x4;
typedef unsigned long long ull;

#define BB 8
#define SS 256
#define MM (BB*SS)     // 2048 token rows
#define HH 1000
#define GG 4000        // 4*H gate dim
#define NP 4096        // padded gate dim (GEMM N)
#define HP 1024        // padded hidden dim (K for recurrent mfma)

__device__ __forceinline__ unsigned short f2bf(float f){
  unsigned u = __builtin_bit_cast(unsigned, f);
  unsigned r = u + 0x7fffu + ((u >> 16) & 1u);     // RNE
  return (unsigned short)(r >> 16);
}
__device__ __forceinline__ float bf2f(unsigned short s){
  unsigned u = ((unsigned)s) << 16;
  return __builtin_bit_cast(float, u);
}
// precise (kfinal, one-shot)
__device__ __forceinline__ float sigf(float x){ return 1.0f / (1.0f + expf(-x)); }
// fast (scan inner loop): v_exp-based, ~1e-6 rel err << bf16 rounding
__device__ __forceinline__ float fsig(float x){ return 1.0f / (1.0f + __expf(-x)); }
__device__ __forceinline__ float ftanh(float x){
  const float e = __expf(-2.0f * fabsf(x));
  const float r = (1.0f - e) / (1.0f + e);
  return x < 0.0f ? -r : r;
}
// all four u16 fields of an 8B granule nonzero? (8B producer store is atomic)
__device__ __forceinline__ bool valid4(ull v){
  return (v & 0xffffull) && (v & 0xffff0000ull) &&
         (v & 0xffff00000000ull) && (v >> 48);
}

__device__ __forceinline__ void async_copy16(const void* g, void* l){
  __builtin_amdgcn_global_load_lds(
      (const __attribute__((address_space(1))) unsigned int*)g,
      (__attribute__((address_space(3))) unsigned int*)l, 16, 0, 0);
}

// ---------------------------------------------------------------- prep ------
__global__ void kzero(unsigned int* __restrict__ p, size_t nwords){
  size_t stride = (size_t)gridDim.x * blockDim.x;
  for (size_t i = (size_t)blockIdx.x*blockDim.x + threadIdx.x; i < nwords; i += stride)
    p[i] = 0u;
}

__global__ void kpadw(const float* __restrict__ src, unsigned short* __restrict__ dst,
                      int K, int Kpad){
  size_t total = (size_t)NP * Kpad;
  size_t stride = (size_t)gridDim.x * blockDim.x;
  for (size_t i = (size_t)blockIdx.x*blockDim.x + threadIdx.x; i < total; i += stride){
    int nrow = (int)(i / Kpad);
    int k    = (int)(i % Kpad);
    float v = (nrow < GG && k < K) ? src[(size_t)nrow*K + k] : 0.0f;
    dst[i] = f2bf(v);
  }
}

__global__ void kgather(const float* __restrict__ emb, const int* __restrict__ x,
                        unsigned short* __restrict__ dst, int E){
  size_t total = (size_t)MM * E;
  size_t stride = (size_t)gridDim.x * blockDim.x;
  for (size_t i = (size_t)blockIdx.x*blockDim.x + threadIdx.x; i < total; i += stride){
    size_t m = i / E, e = i % E;
    dst[i] = f2bf(emb[(size_t)x[m]*E + e]);
  }
}

// in-place decode of inverted-h buffers: per u16, x ? ~x : 0
__global__ void kdecode(ull* __restrict__ p, size_t n64){
  size_t stride = (size_t)gridDim.x * blockDim.x;
  for (size_t i = (size_t)blockIdx.x*blockDim.x + threadIdx.x; i < n64; i += stride){
    const ull v = p[i];
    ull m = 0;
    if (v & 0xffffull)          m |= 0xffffull;
    if (v & 0xffff0000ull)      m |= 0xffff0000ull;
    if (v & 0xffff00000000ull)  m |= 0xffff00000000ull;
    if (v >> 48)                m |= 0xffff000000000000ull;
    p[i] = (~v) & m;
  }
}

// ---------------------------------------------------------------- GEMM ------
__launch_bounds__(256, 2)
__global__ void kgemm(const unsigned short* __restrict__ A,
                      const unsigned short* __restrict__ W,
                      const float* __restrict__ bias,
                      float* __restrict__ out, int Kpad){
  __shared__ __align__(16) unsigned short ldsA[128*64];
  __shared__ __align__(16) unsigned short ldsB[128*64];
  const int tid = threadIdx.x;
  const int w = tid >> 6, l = tid & 63;
  const int wr = w >> 1, wc = w & 1;
  const int tm = blockIdx.x & 15, tn = blockIdx.x >> 4;
  const size_t Kb = (size_t)Kpad * 2;
  const int nk = Kpad >> 6;

  f32x4 acc[4][4];
#pragma unroll
  for (int a = 0; a < 4; ++a)
#pragma unroll
    for (int b = 0; b < 4; ++b) acc[a][b] = (f32x4){0.f,0.f,0.f,0.f};

  for (int kt = 0; kt < nk; ++kt){
#pragma unroll
    for (int c = 0; c < 4; ++c){
      const int chunk = c*4 + w;
      const int flat = chunk*1024 + l*16;
      const int row = flat >> 7;
      const int off = flat & 127;
      const int soff = off ^ ((row & 7) << 4);
      async_copy16((const char*)A + (size_t)(tm*128+row)*Kb + (size_t)kt*128 + soff,
                   (char*)ldsA + chunk*1024);
      async_copy16((const char*)W + (size_t)(tn*128+row)*Kb + (size_t)kt*128 + soff,
                   (char*)ldsB + chunk*1024);
    }
    asm volatile("s_waitcnt vmcnt(0)" ::: "memory");
    __syncthreads();

#pragma unroll
    for (int ks = 0; ks < 2; ++ks){
      short8 af[4], bf[4];
#pragma unroll
      for (int mf = 0; mf < 4; ++mf){
        const int row = wr*64 + mf*16 + (l & 15);
        const int off = ((ks*32 + (l>>4)*8)*2) ^ ((row & 7) << 4);
        af[mf] = *(const short8*)((const char*)ldsA + row*128 + off);
      }
#pragma unroll
      for (int nf = 0; nf < 4; ++nf){
        const int row = wc*64 + nf*16 + (l & 15);
        const int off = ((ks*32 + (l>>4)*8)*2) ^ ((row & 7) << 4);
        bf[nf] = *(const short8*)((const char*)ldsB + row*128 + off);
      }
#pragma unroll
      for (int mf = 0; mf < 4; ++mf)
#pragma unroll
        for (int nf = 0; nf < 4; ++nf)
          acc[mf][nf] = __builtin_amdgcn_mfma_f32_16x16x32_bf16(
              af[mf], bf[nf], acc[mf][nf], 0, 0, 0);
    }
    __syncthreads();
  }

#pragma unroll
  for (int nf = 0; nf < 4; ++nf){
    const int n = tn*128 + wc*64 + nf*16 + (l & 15);
    if (n < GG){
      const float bv = bias[n];
#pragma unroll
      for (int mf = 0; mf < 4; ++mf){
#pragma unroll
        for (int q = 0; q < 4; ++q){
          const int m = tm*128 + wr*64 + mf*16 + (l>>4)*4 + q;
          out[(size_t)m*GG + n] = acc[mf][nf][q] + bv;
        }
      }
    }
  }
}

// ---------------------------------------------------------------- scan ------
struct LstmDesc {
  const float* xg;          // [2048][4000] f32 (bias included)
  const float* whh;         // [4000][1000] f32
  unsigned short* hbuf;     // INVERTED bf16 h sequence buffer (write-once/slot)
  int hstride;              // row stride in elems (1024 or 2048)
  int joff;                 // column offset in hbuf
  int rev;                  // reversed scan
};
struct ScanArgs {
  LstmDesc d[3];
  unsigned int* asg;        // [0..7]=per-XCD rank cnt, [8]=grid bar, [9]=spill
  int nl;                   // number of live LSTMs
  int nwg;                  // grid size (participants in grid barrier)
};

// Grid 256 x 512 thr (all co-resident). Work assigned by PHYSICAL XCD so each
// LSTM's 32 WGs share one per-XCD L2 (spill list covers any placement).
// Sync: dataflow poll on inverted h 8B granules -- sc0 (local L2) probe,
// then sc0 sc1 (L3 truth) for pending; worst case == pure-L3 polling.
__launch_bounds__(512, 2)
__global__ void kscan(ScanArgs args){
  __shared__ __align__(16) unsigned short h_lds[2][8][HP];  // double-buffered
  __shared__ float ex[8][128];                              // per-wave gates
  __shared__ unsigned short exh[8][32];                     // per-wave h out
  __shared__ int s_lstm, s_slice;
  const int tid = threadIdx.x;

  if (tid == 0){
    unsigned xcc = 0;
    asm volatile("s_getreg_b32 %0, hwreg(HW_REG_XCC_ID)" : "=s"(xcc));
    xcc &= 7u;
    int lstm = -1, slice = -1;
    const unsigned r = __hip_atomic_fetch_add(&args.asg[xcc], 1u,
                          __ATOMIC_RELAXED, __HIP_MEMORY_SCOPE_AGENT);
    asm volatile("s_waitcnt vmcnt(0)" ::: "memory");
    if ((int)xcc < args.nl && r < 32u){ lstm = (int)xcc; slice = (int)r; }
    __hip_atomic_fetch_add(&args.asg[8], 1u,
                           __ATOMIC_RELAXED, __HIP_MEMORY_SCOPE_AGENT);
    while (__hip_atomic_load(&args.asg[8], __ATOMIC_RELAXED,
                             __HIP_MEMORY_SCOPE_AGENT) < (unsigned)args.nwg)
      __builtin_amdgcn_s_sleep(1);
    if (lstm < 0){
      unsigned s = __hip_atomic_fetch_add(&args.asg[9], 1u,
                      __ATOMIC_RELAXED, __HIP_MEMORY_SCOPE_AGENT);
      asm volatile("s_waitcnt vmcnt(0)" ::: "memory");
      for (int ll = 0; ll < args.nl; ++ll){
        unsigned c = __hip_atomic_load(&args.asg[ll], __ATOMIC_RELAXED,
                                       __HIP_MEMORY_SCOPE_AGENT);
        const unsigned cl = c < 32u ? c : 32u;
        const unsigned un = 32u - cl;
        if (s < un){ lstm = ll; slice = (int)(cl + s); break; }
        s -= un;
      }
    }
    s_lstm = lstm; s_slice = slice;
  }
  __syncthreads();
  const int lstm = s_lstm, slice = s_slice;
  if (lstm < 0) return;                        // surplus WG
  const LstmDesc D = args.d[lstm];

  const int wv = tid >> 6, l = tid & 63;
  const int col = l & 15, g4 = l >> 4;
  const int gate = col >> 2, jl = col & 3;
  const int j = slice*32 + wv*4 + jl;          // hidden unit for this mfma col
  const int n = gate*HH + j;                   // gate-column in [0,4000)
  const bool jv = (j < HH);

  // ---- one-time: load Whh B-fragments (lane holds B[k][col]=Whh[n][k]) ----
  short8 wf[32];
#pragma unroll
  for (int ks = 0; ks < 32; ++ks){
    short8 v = (short8){0,0,0,0,0,0,0,0};
    const int kb = ks*32 + g4*8;
    if (jv && kb < HH){
      const float* s = D.whh + (size_t)n*HH + kb;
#pragma unroll
      for (int i = 0; i < 8; ++i) v[i] = (short)f2bf(s[i]);
    }
    wf[ks] = v;
  }

  // per-thread poll-granule constants (4 x 8B covers 16KB h tile)
  int chr_[4], coff_[4], ldso_[4];
  bool cneed_[4];
#pragma unroll
  for (int cc = 0; cc < 4; ++cc){
    const int fb = (cc*512 + tid) * 8;         // byte in 16KB tile
    chr_[cc]  = fb >> 11;                      // batch row 0..7
    coff_[cc] = fb & 2047;                     // byte within row window
    cneed_[cc] = (coff_[cc] < 2000);           // col < 1000 => written
    ldso_[cc] = chr_[cc]*2048 + (coff_[cc] ^ ((chr_[cc] & 7) << 4));
  }

  const int arow = l & 15;                     // A-fragment batch row
  const bool av = arow < 8;
  const int aswz = (arow & 7) << 4;
  float c_reg = 0.f;                           // cell state (lanes 0..31)
  const int ub = l & 7, ujl = (l >> 3) & 3;
  const int ubase = slice*32 + wv*4;           // first unit of this wave
  const bool sv = (ubase < HH);                // wave's 4 units valid

  // xg for t=0 (f32, bias included): 4 batch rows per lane
  float xgv[4] = {0.f,0.f,0.f,0.f};
  {
    const int pos0 = D.rev ? (SS-1) : 0;
    if (g4 < 2 && jv){
#pragma unroll
      for (int q = 0; q < 4; ++q)
        xgv[q] = D.xg[(size_t)((g4*4+q)*SS + pos0)*GG + n];
    }
  }

  for (int t = 0; t < SS; ++t){
    const int pos  = D.rev ? (SS-1 - t) : t;
    const int ppos = D.rev ? (pos + 1) : (pos - 1);
    const int buf = t & 1;

    // ---- acquire h_prev: sc0 (local L2) probe, then sc0 sc1 (L3) for
    //      still-pending granules. t==0: h(-1)=0.
    ull val[4] = {0ull, 0ull, 0ull, 0ull};
    if (t > 0){
      const char* src_[4];
      unsigned pend = 0;
#pragma unroll
      for (int cc = 0; cc < 4; ++cc){
        src_[cc] = (const char*)D.hbuf
            + ((size_t)(chr_[cc]*SS + ppos)*D.hstride + D.joff)*2 + coff_[cc];
        if (cneed_[cc]) pend |= 1u << cc;
      }
      while (pend){
        ull tmp[4];
        // phase 1: local-L2 probe (fast when producer is same-XCD)
#pragma unroll
        for (int cc = 0; cc < 4; ++cc)
          if (pend & (1u << cc))
            asm volatile("global_load_dwordx2 %0, %1, off sc0"
                         : "=v"(tmp[cc]) : "v"(src_[cc]) : "memory");
        asm volatile("s_waitcnt vmcnt(0)" ::: "memory");
#pragma unroll
        for (int cc = 0; cc < 4; ++cc)
          if ((pend & (1u << cc)) && valid4(tmp[cc])){
            val[cc] = ~tmp[cc];
            pend &= ~(1u << cc);
          }
        if (!pend) break;
        // phase 2: coherence-point read (truth under any placement)
#pragma unroll
        for (int cc = 0; cc < 4; ++cc)
          if (pend & (1u << cc))
            asm volatile("global_load_dwordx2 %0, %1, off sc0 sc1"
                         : "=v"(tmp[cc]) : "v"(src_[cc]) : "memory");
        asm volatile("s_waitcnt vmcnt(0)" ::: "memory");
#pragma unroll
        for (int cc = 0; cc < 4; ++cc)
          if ((pend & (1u << cc)) && valid4(tmp[cc])){
            val[cc] = ~tmp[cc];
            pend &= ~(1u << cc);
          }
      }
    }
#pragma unroll
    for (int cc = 0; cc < 4; ++cc)
      *(ull*)((char*)h_lds + buf*16384 + ldso_[cc]) = val[cc];
    __syncthreads();

    // gates = h_prev @ Whh^T  (K=1024, two independent 16-mfma chains)
    const char* abase = (const char*)h_lds + buf*16384 + arow*2048;
    f32x4 a0 = (f32x4){0.f,0.f,0.f,0.f};
    f32x4 a1 = (f32x4){0.f,0.f,0.f,0.f};
#pragma unroll
    for (int ks = 0; ks < 16; ++ks){
      const int o0 = (((2*ks  )*64) | (g4*16)) ^ aswz;
      const int o1 = (((2*ks+1)*64) | (g4*16)) ^ aswz;
      short8 s0 = av ? *(const short8*)(abase + o0) : (short8){0,0,0,0,0,0,0,0};
      short8 s1 = av ? *(const short8*)(abase + o1) : (short8){0,0,0,0,0,0,0,0};
      a0 = __builtin_amdgcn_mfma_f32_16x16x32_bf16(s0, wf[2*ks  ], a0, 0, 0, 0);
      a1 = __builtin_amdgcn_mfma_f32_16x16x32_bf16(s1, wf[2*ks+1], a1, 0, 0, 0);
    }

    // exchange i/f/g/o within wave (wave-local LDS: no block barrier needed)
    if (g4 < 2){
#pragma unroll
      for (int q = 0; q < 4; ++q)
        ex[wv][(jl*4 + gate)*8 + (g4*4 + q)] = a0[q] + a1[q] + xgv[q];
    }

    if (l < 32){
      const float iv = ex[wv][(ujl*4 + 0)*8 + ub];
      const float fv = ex[wv][(ujl*4 + 1)*8 + ub];
      const float gv = ex[wv][(ujl*4 + 2)*8 + ub];
      const float ov = ex[wv][(ujl*4 + 3)*8 + ub];
      c_reg = fsig(fv)*c_reg + fsig(iv)*ftanh(gv);
      const float h = fsig(ov)*ftanh(c_reg);
      exh[wv][ub*4 + ujl] = f2bf(h);
    }
    // packed 8B INVERTED h dual-store: agent-scope (L3 truth) FIRST, then
    // plain store refreshing the local-L2 line for same-XCD sc0 readers.
    // Identical bytes -> coherent under any interleaving/eviction.
    if (l < 8 && sv){
      const ull hv = ~(*(const ull*)&exh[wv][l*4]);
      ull* dst = (ull*)&D.hbuf[(size_t)(l*SS + pos)*D.hstride + D.joff + ubase];
      asm volatile("global_store_dwordx2 %0, %1, off sc0 sc1\n\t"
                   "global_store_dwordx2 %0, %1, off"
                   :: "v"(dst), "v"(hv) : "memory");
    }

    // prefetch xg for t+1 (latency hides under the next poll)
    float xgn[4] = {0.f,0.f,0.f,0.f};
    if (t+1 < SS && g4 < 2 && jv){
      const int npos = D.rev ? (pos - 1) : (pos + 1);
#pragma unroll
      for (int q = 0; q < 4; ++q)
        xgn[q] = D.xg[(size_t)((g4*4+q)*SS + npos)*GG + n];
    }
#pragma unroll
    for (int q = 0; q < 4; ++q) xgv[q] = xgn[q];
  }
}

// --------------------------------------------------------------- final ------
__global__ void kfinal(const unsigned short* __restrict__ hw1,
                       const unsigned short* __restrict__ hpf1,
                       const float* __restrict__ xgr1,
                       const float* __restrict__ w1, const float* __restrict__ b1,
                       const float* __restrict__ w2, const float* __restrict__ b2,
                       const float* __restrict__ wc, const float* __restrict__ bc,
                       float* __restrict__ out){
  __shared__ float red[256];
  const int tid = threadIdx.x;
  for (int b = 0; b < BB; ++b){
    const size_t r = (size_t)(b*SS + (SS-1));
    float ps = 0.f, wsm = 0.f;
    for (int j = tid; j < HH; j += 256){
      // h buffers hold inverted bf16 -> decode (x ? ~x : 0)
      unsigned short hp = hpf1[r*1024 + j];
      unsigned short hw = hw1 [r*1024 + j];
      hp = hp ? (unsigned short)~hp : (unsigned short)0;
      hw = hw ? (unsigned short)~hw : (unsigned short)0;
      ps  += bf2f(hp) * w2[j];
      // para reverse layer-1, step 0 (h0=c0=0): closed form from xg
      const float iv = xgr1[r*GG + j];
      const float gv = xgr1[r*GG + 2000 + j];
      const float ov = xgr1[r*GG + 3000 + j];
      const float cc = sigf(iv)*tanhf(gv);
      ps  += sigf(ov)*tanhf(cc) * w2[HH + j];
      wsm += bf2f(hw) * w1[j];
    }
    red[tid] = ps; __syncthreads();
    for (int s = 128; s > 0; s >>= 1){ if (tid < s) red[tid] += red[tid+s]; __syncthreads(); }
    const float PS = red[0]; __syncthreads();
    red[tid] = wsm; __syncthreads();
    for (int s = 128; s > 0; s >>= 1){ if (tid < s) red[tid] += red[tid+s]; __syncthreads(); }
    const float WS = red[0]; __syncthreads();
    if (tid == 0)
      out[b] = wc[0]*(PS + b2[0]) + wc[1]*(WS + b1[0]) + bc[0];
    __syncthreads();
  }
}

// --------------------------------------------------------------- host -------
extern "C" void kernel_launch(void* const* d_in, const int* in_sizes, int n_in,
                              void* d_out, int out_size, void* d_ws, size_t ws_size,
                              hipStream_t stream){
  const int*   x      = (const int*)  d_in[0];
  const float* embw   = (const float*)d_in[1];
  const float* embp   = (const float*)d_in[2];
  const float* l1Wih0 = (const float*)d_in[3];
  const float* l1Whh0 = (const float*)d_in[4];
  const float* l1b0   = (const float*)d_in[5];
  const float* l1Wih1 = (const float*)d_in[6];
  const float* l1Whh1 = (const float*)d_in[7];
  const float* l1b1   = (const float*)d_in[8];
  const float* f0Wih  = (const float*)d_in[9];
  const float* f0Whh  = (const float*)d_in[10];
  const float* f0b    = (const float*)d_in[11];
  const float* r0Wih  = (const float*)d_in[12];
  const float* r0Whh  = (const float*)d_in[13];
  const float* r0b    = (const float*)d_in[14];
  const float* f1Wih  = (const float*)d_in[15];
  const float* f1Whh  = (const float*)d_in[16];
  const float* f1b    = (const float*)d_in[17];
  const float* r1Wih  = (const float*)d_in[18];
  const float* r1Whh  = (const float*)d_in[19];
  const float* r1b    = (const float*)d_in[20];
  const float* w1     = (const float*)d_in[21];
  const float* b1     = (const float*)d_in[22];
  const float* w2     = (const float*)d_in[23];
  const float* b2     = (const float*)d_in[24];
  const float* wc     = (const float*)d_in[25];
  const float* bc     = (const float*)d_in[26];
  float* out = (float*)d_out;
  (void)in_sizes; (void)n_in; (void)out_size; (void)ws_size;

  char* ws = (char*)d_ws;
  size_t off = 0;
  auto alloc = [&](size_t bytes)->char*{
    char* p = ws + off;
    off += (bytes + 255) & ~(size_t)255;
    return p;
  };
  // padded bf16 Wih copies [4096][Kpad]
  unsigned short* pw_l1Wih0 = (unsigned short*)alloc((size_t)NP*512*2);
  unsigned short* pw_f0Wih  = (unsigned short*)alloc((size_t)NP*768*2);
  unsigned short* pw_r0Wih  = (unsigned short*)alloc((size_t)NP*768*2);
  unsigned short* pw_l1Wih1 = (unsigned short*)alloc((size_t)NP*1024*2);
  unsigned short* pw_f1Wih  = (unsigned short*)alloc((size_t)NP*2048*2);
  unsigned short* pw_r1Wih  = (unsigned short*)alloc((size_t)NP*2048*2);
  // gathered embeddings (bf16)
  unsigned short* a_w = (unsigned short*)alloc((size_t)MM*512*2);
  unsigned short* a_p = (unsigned short*)alloc((size_t)MM*768*2);
  // gate pre-activations (f32), reused across the two layers
  float* xg0 = (float*)alloc((size_t)MM*GG*4);
  float* xg1 = (float*)alloc((size_t)MM*GG*4);
  float* xg2 = (float*)alloc((size_t)MM*GG*4);
  // h sequence buffers (inverted bf16) + assignment scratch -- zeroed per call
  char* zbase = ws + off;
  unsigned short* h_w0  = (unsigned short*)alloc((size_t)MM*1024*2);
  unsigned short* cat0  = (unsigned short*)alloc((size_t)MM*2048*2); // [fwd|rev|pad]
  unsigned short* h_w1  = (unsigned short*)alloc((size_t)MM*1024*2);
  unsigned short* h_pf1 = (unsigned short*)alloc((size_t)MM*1024*2);
  unsigned int* asgB = (unsigned int*)alloc(16*4);
  unsigned int* asgD = (unsigned int*)alloc(16*4);
  size_t zwords = (size_t)((ws + off) - zbase) / 4;

  kzero<<<dim3(1024), dim3(256), 0, stream>>>((unsigned int*)zbase, zwords);
  kpadw<<<dim3(1024), dim3(256), 0, stream>>>(l1Wih0, pw_l1Wih0, 512, 512);
  kpadw<<<dim3(1024), dim3(256), 0, stream>>>(f0Wih,  pw_f0Wih,  768, 768);
  kpadw<<<dim3(1024), dim3(256), 0, stream>>>(r0Wih,  pw_r0Wih,  768, 768);
  kpadw<<<dim3(1024), dim3(256), 0, stream>>>(l1Wih1, pw_l1Wih1, 1000, 1024);
  kpadw<<<dim3(1024), dim3(256), 0, stream>>>(f1Wih,  pw_f1Wih,  2000, 2048);
  kpadw<<<dim3(1024), dim3(256), 0, stream>>>(r1Wih,  pw_r1Wih,  2000, 2048);
  kgather<<<dim3(512), dim3(256), 0, stream>>>(embw, x, a_w, 512);
  kgather<<<dim3(512), dim3(256), 0, stream>>>(embp, x, a_p, 768);

  // layer-0 projections
  kgemm<<<dim3(512), dim3(256), 0, stream>>>(a_w, pw_l1Wih0, l1b0, xg0, 512);
  kgemm<<<dim3(512), dim3(256), 0, stream>>>(a_p, pw_f0Wih,  f0b,  xg1, 768);
  kgemm<<<dim3(512), dim3(256), 0, stream>>>(a_p, pw_r0Wih,  r0b,  xg2, 768);

  // layer-0 scans: word fwd (XCD0), para fwd (XCD1), para rev (XCD2)
  {
    ScanArgs sa;
    sa.d[0] = LstmDesc{xg0, l1Whh0, h_w0, 1024, 0, 0};
    sa.d[1] = LstmDesc{xg1, f0Whh,  cat0, 2048, 0, 0};
    sa.d[2] = LstmDesc{xg2, r0Whh,  cat0, 2048, 1000, 1};
    sa.asg = asgB; sa.nl = 3; sa.nwg = 256;
    kscan<<<dim3(256), dim3(512), 0, stream>>>(sa);
  }

  // decode inverted h (h_w0 + cat0 are contiguous) before layer-1 GEMMs
  kdecode<<<dim3(2048), dim3(256), 0, stream>>>(
      (ull*)h_w0, ((size_t)MM*1024 + (size_t)MM*2048) / 4);

  // layer-1 projections (A = layer-0 h sequences, decoded)
  kgemm<<<dim3(512), dim3(256), 0, stream>>>(h_w0, pw_l1Wih1, l1b1, xg0, 1024);
  kgemm<<<dim3(512), dim3(256), 0, stream>>>(cat0, pw_f1Wih,  f1b,  xg1, 2048);
  kgemm<<<dim3(512), dim3(256), 0, stream>>>(cat0, pw_r1Wih,  r1b,  xg2, 2048);

  // layer-1 scans: word fwd (XCD0) + para fwd (XCD1); para rev -> kfinal
  {
    ScanArgs sa;
    sa.d[0] = LstmDesc{xg0, l1Whh1, h_w1,  1024, 0, 0};
    sa.d[1] = LstmDesc{xg1, f1Whh,  h_pf1, 1024, 0, 0};
    sa.d[2] = LstmDesc{nullptr, nullptr, nullptr, 1024, 0, 0};
    sa.asg = asgD; sa.nl = 2; sa.nwg = 256;
    kscan<<<dim3(256), dim3(512), 0, stream>>>(sa);
  }

  kfinal<<<dim3(1), dim3(256), 0, stream>>>(h_w1, h_pf1, xg2,
                                            w1, b1, w2, b2, wc, bc, out);
}

// Round 10
// 2143.888 us; speedup vs baseline: 3.2625x; 3.2625x over previous
//
#include <hip/hip_runtime.h>
#include <stdint.h>
#include <math.h>

// ---------------------------------------------------------------------------
// StoryJudger2: word branch (2x LSTM H=1000) + paragraph branch (2x biLSTM)
// B=8, S=256, V=50257, E=512, P=768, H=1000.
//
// Strategy (R4 structure, best measured; r1 GEMM replaced by 8-row kxg8):
//  - Input projections xg = A @ Wih^T + b as bf16 MFMA GEMMs (f32 out).
//  - Recurrent scans: persistent kernel, 32 WGs x 512 thr per LSTM, Whh
//    register-resident as MFMA B-fragments. NO barrier: h stored BIT-INVERTED
//    (8B agent-scope stores) to a write-once position-indexed buffer;
//    consumers poll the exact words they need (agent-scope 8B loads).
//    0x0000 == not-written (|h|<1 never inverts to 0; slots pre-zeroed).
//    One __syncthreads per step (double-buffered LDS h tile).
//  - h buffers hold INVERTED bf16 -> kdecode before layer-1 GEMMs; kfinal
//    decodes inline.
//  - para reverse layer-1 only needs step 0 (h0=c0=0) at position 255 ->
//    xg for those 8 rows computed by kxg8 (one wave per gate column);
//    closed form applied in kfinal.
// ---------------------------------------------------------------------------

typedef __attribute__((ext_vector_type(8))) short short8;
typedef __attribute__((ext_vector_type(4))) float f32x4;
typedef __attribute__((ext_vector_type(4))) unsigned int u32x4;
typedef unsigned long long ull;

#define BB 8
#define SS 256
#define MM (BB*SS)     // 2048 token rows
#define HH 1000
#define GG 4000        // 4*H gate dim
#define NP 4096        // padded gate dim (GEMM N)
#define HP 1024        // padded hidden dim (K for recurrent mfma)

__device__ __forceinline__ unsigned short f2bf(float f){
  unsigned u = __builtin_bit_cast(unsigned, f);
  unsigned r = u + 0x7fffu + ((u >> 16) & 1u);     // RNE
  return (unsigned short)(r >> 16);
}
__device__ __forceinline__ float bf2f(unsigned short s){
  unsigned u = ((unsigned)s) << 16;
  return __builtin_bit_cast(float, u);
}
// precise (kfinal, one-shot)
__device__ __forceinline__ float sigf(float x){ return 1.0f / (1.0f + expf(-x)); }
// fast (scan inner loop): v_exp-based, ~1e-6 rel err << bf16 rounding
__device__ __forceinline__ float fsig(float x){ return 1.0f / (1.0f + __expf(-x)); }
__device__ __forceinline__ float ftanh(float x){
  const float e = __expf(-2.0f * fabsf(x));
  const float r = (1.0f - e) / (1.0f + e);
  return x < 0.0f ? -r : r;
}
// all four u16 fields nonzero?
__device__ __forceinline__ bool valid4(ull v){
  return (v & 0xffffull) && (v & 0xffff0000ull) &&
         (v & 0xffff00000000ull) && (v >> 48);
}

__device__ __forceinline__ void async_copy16(const void* g, void* l){
  __builtin_amdgcn_global_load_lds(
      (const __attribute__((address_space(1))) unsigned int*)g,
      (__attribute__((address_space(3))) unsigned int*)l, 16, 0, 0);
}

// ---------------------------------------------------------------- prep ------
__global__ void kzero(unsigned int* __restrict__ p, size_t nwords){
  size_t stride = (size_t)gridDim.x * blockDim.x;
  for (size_t i = (size_t)blockIdx.x*blockDim.x + threadIdx.x; i < nwords; i += stride)
    p[i] = 0u;
}

__global__ void kpadw(const float* __restrict__ src, unsigned short* __restrict__ dst,
                      int K, int Kpad){
  size_t total = (size_t)NP * Kpad;
  size_t stride = (size_t)gridDim.x * blockDim.x;
  for (size_t i = (size_t)blockIdx.x*blockDim.x + threadIdx.x; i < total; i += stride){
    int nrow = (int)(i / Kpad);
    int k    = (int)(i % Kpad);
    float v = (nrow < GG && k < K) ? src[(size_t)nrow*K + k] : 0.0f;
    dst[i] = f2bf(v);
  }
}

__global__ void kgather(const float* __restrict__ emb, const int* __restrict__ x,
                        unsigned short* __restrict__ dst, int E){
  size_t total = (size_t)MM * E;
  size_t stride = (size_t)gridDim.x * blockDim.x;
  for (size_t i = (size_t)blockIdx.x*blockDim.x + threadIdx.x; i < total; i += stride){
    size_t m = i / E, e = i % E;
    dst[i] = f2bf(emb[(size_t)x[m]*E + e]);
  }
}

// in-place decode of inverted-h buffers: per u16, x ? ~x : 0
__global__ void kdecode(ull* __restrict__ p, size_t n64){
  size_t stride = (size_t)gridDim.x * blockDim.x;
  for (size_t i = (size_t)blockIdx.x*blockDim.x + threadIdx.x; i < n64; i += stride){
    const ull v = p[i];
    ull m = 0;
    if (v & 0xffffull)          m |= 0xffffull;
    if (v & 0xffff0000ull)      m |= 0xffff0000ull;
    if (v & 0xffff00000000ull)  m |= 0xffff00000000ull;
    if (v >> 48)                m |= 0xffff000000000000ull;
    p[i] = (~v) & m;
  }
}

// xg_r1 is only needed at the 8 rows (b*SS + SS-1) for kfinal's closed-form
// step: compute those rows directly from f32 weights x decoded cat0.
// One wave per gate-column n; lanes stride K; butterfly-reduce; lane 0 writes.
__global__ void kxg8(const float* __restrict__ Wih,   // [4000][2000] f32
                     const float* __restrict__ bias,  // [4000]
                     const unsigned short* __restrict__ cat, // decoded cat0
                     float* __restrict__ xg){
  const int wv = threadIdx.x >> 6, l = threadIdx.x & 63;
  const int n = blockIdx.x*4 + wv;
  if (n >= GG) return;
  float acc[BB];
#pragma unroll
  for (int b = 0; b < BB; ++b) acc[b] = 0.f;
  for (int k = l; k < 2000; k += 64){
    const float w = Wih[(size_t)n*2000 + k];
#pragma unroll
    for (int b = 0; b < BB; ++b)
      acc[b] += w * bf2f(cat[(size_t)(b*SS + SS-1)*2048 + k]);
  }
#pragma unroll
  for (int b = 0; b < BB; ++b)
    for (int off = 32; off; off >>= 1) acc[b] += __shfl_down(acc[b], off);
  if (l == 0){
#pragma unroll
    for (int b = 0; b < BB; ++b)
      xg[(size_t)(b*SS + SS-1)*GG + n] = acc[b] + bias[n];
  }
}

// ---------------------------------------------------------------- GEMM ------
__launch_bounds__(256, 2)
__global__ void kgemm(const unsigned short* __restrict__ A,
                      const unsigned short* __restrict__ W,
                      const float* __restrict__ bias,
                      float* __restrict__ out, int Kpad){
  __shared__ __align__(16) unsigned short ldsA[128*64];
  __shared__ __align__(16) unsigned short ldsB[128*64];
  const int tid = threadIdx.x;
  const int w = tid >> 6, l = tid & 63;
  const int wr = w >> 1, wc = w & 1;
  const int tm = blockIdx.x & 15, tn = blockIdx.x >> 4;
  const size_t Kb = (size_t)Kpad * 2;
  const int nk = Kpad >> 6;

  f32x4 acc[4][4];
#pragma unroll
  for (int a = 0; a < 4; ++a)
#pragma unroll
    for (int b = 0; b < 4; ++b) acc[a][b] = (f32x4){0.f,0.f,0.f,0.f};

  for (int kt = 0; kt < nk; ++kt){
#pragma unroll
    for (int c = 0; c < 4; ++c){
      const int chunk = c*4 + w;
      const int flat = chunk*1024 + l*16;
      const int row = flat >> 7;
      const int off = flat & 127;
      const int soff = off ^ ((row & 7) << 4);
      async_copy16((const char*)A + (size_t)(tm*128+row)*Kb + (size_t)kt*128 + soff,
                   (char*)ldsA + chunk*1024);
      async_copy16((const char*)W + (size_t)(tn*128+row)*Kb + (size_t)kt*128 + soff,
                   (char*)ldsB + chunk*1024);
    }
    asm volatile("s_waitcnt vmcnt(0)" ::: "memory");
    __syncthreads();

#pragma unroll
    for (int ks = 0; ks < 2; ++ks){
      short8 af[4], bf[4];
#pragma unroll
      for (int mf = 0; mf < 4; ++mf){
        const int row = wr*64 + mf*16 + (l & 15);
        const int off = ((ks*32 + (l>>4)*8)*2) ^ ((row & 7) << 4);
        af[mf] = *(const short8*)((const char*)ldsA + row*128 + off);
      }
#pragma unroll
      for (int nf = 0; nf < 4; ++nf){
        const int row = wc*64 + nf*16 + (l & 15);
        const int off = ((ks*32 + (l>>4)*8)*2) ^ ((row & 7) << 4);
        bf[nf] = *(const short8*)((const char*)ldsB + row*128 + off);
      }
#pragma unroll
      for (int mf = 0; mf < 4; ++mf)
#pragma unroll
        for (int nf = 0; nf < 4; ++nf)
          acc[mf][nf] = __builtin_amdgcn_mfma_f32_16x16x32_bf16(
              af[mf], bf[nf], acc[mf][nf], 0, 0, 0);
    }
    __syncthreads();
  }

#pragma unroll
  for (int nf = 0; nf < 4; ++nf){
    const int n = tn*128 + wc*64 + nf*16 + (l & 15);
    if (n < GG){
      const float bv = bias[n];
#pragma unroll
      for (int mf = 0; mf < 4; ++mf){
#pragma unroll
        for (int q = 0; q < 4; ++q){
          const int m = tm*128 + wr*64 + mf*16 + (l>>4)*4 + q;
          out[(size_t)m*GG + n] = acc[mf][nf][q] + bv;
        }
      }
    }
  }
}

// ---------------------------------------------------------------- scan ------
struct LstmDesc {
  const float* xg;          // [2048][4000] f32 (bias included)
  const float* whh;         // [4000][1000] f32
  unsigned short* hbuf;     // INVERTED bf16 h sequence buffer (write-once/slot)
  int hstride;              // row stride in elems (1024 or 2048)
  int joff;                 // column offset in hbuf
  int rev;                  // reversed scan
};
struct ScanArgs {
  LstmDesc d[3];
};

// 32 WGs x 512 threads (8 waves) per LSTM; each wave owns 4 hidden units x
// 4 gates (16 MFMA cols), Whh slice register-resident for all 256 steps.
// Sync: dataflow poll on inverted h words; one __syncthreads per step.
__launch_bounds__(512, 2)
__global__ void kscan(ScanArgs args){
  __shared__ __align__(16) unsigned short h_lds[2][8][HP];  // double-buffered
  __shared__ float ex[8][128];                              // per-wave gates
  __shared__ unsigned short exh[8][32];                     // per-wave h out
  const int tid = threadIdx.x;
  const int wv = tid >> 6, l = tid & 63;
  const int lstm = blockIdx.x >> 5, slice = blockIdx.x & 31;
  const LstmDesc D = args.d[lstm];

  const int col = l & 15, g4 = l >> 4;
  const int gate = col >> 2, jl = col & 3;
  const int j = slice*32 + wv*4 + jl;          // hidden unit for this mfma col
  const int n = gate*HH + j;                   // gate-column in [0,4000)
  const bool jv = (j < HH);

  // ---- one-time: load Whh B-fragments (lane holds B[k][col]=Whh[n][k]) ----
  short8 wf[32];
#pragma unroll
  for (int ks = 0; ks < 32; ++ks){
    short8 v = (short8){0,0,0,0,0,0,0,0};
    const int kb = ks*32 + g4*8;
    if (jv && kb < HH){
      const float* s = D.whh + (size_t)n*HH + kb;
#pragma unroll
      for (int i = 0; i < 8; ++i) v[i] = (short)f2bf(s[i]);
    }
    wf[ks] = v;
  }

  // per-thread staging-chunk constants (4 x 8B covers 16KB h tile)
  int chr_[4], coff_[4], ldso_[4];
  bool cneed_[4];
#pragma unroll
  for (int cc = 0; cc < 4; ++cc){
    const int fb = (cc*512 + tid) * 8;         // byte in 16KB tile
    chr_[cc]  = fb >> 11;                      // batch row 0..7
    coff_[cc] = fb & 2047;                     // byte within row window
    cneed_[cc] = (coff_[cc] < 2000);           // col < 1000 => written
    ldso_[cc] = chr_[cc]*2048 + (coff_[cc] ^ ((chr_[cc] & 7) << 4));
  }

  const int arow = l & 15;                     // A-fragment batch row
  const bool av = arow < 8;
  const int aswz = (arow & 7) << 4;
  float c_reg = 0.f;                           // cell state (lanes 0..31)
  const int ub = l & 7, ujl = (l >> 3) & 3;
  const int ubase = slice*32 + wv*4;           // first unit of this wave
  const bool sv = (ubase < HH);                // wave's 4 units valid

  // xg for t=0 (f32, bias included): 4 batch rows per lane
  float xgv[4] = {0.f,0.f,0.f,0.f};
  {
    const int pos0 = D.rev ? (SS-1) : 0;
    if (g4 < 2 && jv){
#pragma unroll
      for (int q = 0; q < 4; ++q)
        xgv[q] = D.xg[(size_t)((g4*4+q)*SS + pos0)*GG + n];
    }
  }

  for (int t = 0; t < SS; ++t){
    const int pos  = D.rev ? (SS-1 - t) : t;
    const int ppos = D.rev ? (pos + 1) : (pos - 1);
    const int buf = t & 1;

    // ---- acquire h_prev by polling the inverted data words themselves ----
    ull val[4] = {0ull, 0ull, 0ull, 0ull};
    if (t > 0){
      const char* src_[4];
      unsigned pend = 0;
#pragma unroll
      for (int cc = 0; cc < 4; ++cc){
        src_[cc] = (const char*)D.hbuf
            + ((size_t)(chr_[cc]*SS + ppos)*D.hstride + D.joff)*2 + coff_[cc];
        if (cneed_[cc]) pend |= 1u << cc;
      }
      while (pend){
        ull tmp[4];
#pragma unroll
        for (int cc = 0; cc < 4; ++cc)
          if (pend & (1u << cc))
            tmp[cc] = __hip_atomic_load((const ull*)src_[cc],
                                        __ATOMIC_RELAXED, __HIP_MEMORY_SCOPE_AGENT);
#pragma unroll
        for (int cc = 0; cc < 4; ++cc)
          if ((pend & (1u << cc)) && valid4(tmp[cc])){
            val[cc] = ~tmp[cc];                // decode
            pend &= ~(1u << cc);
          }
      }
    }
#pragma unroll
    for (int cc = 0; cc < 4; ++cc)
      *(ull*)((char*)h_lds + buf*16384 + ldso_[cc]) = val[cc];
    __syncthreads();

    // gates = h_prev @ Whh^T  (K=1024, two independent 16-mfma chains)
    const char* abase = (const char*)h_lds + buf*16384 + arow*2048;
    f32x4 a0 = (f32x4){0.f,0.f,0.f,0.f};
    f32x4 a1 = (f32x4){0.f,0.f,0.f,0.f};
#pragma unroll
    for (int ks = 0; ks < 16; ++ks){
      const int o0 = (((2*ks  )*64) | (g4*16)) ^ aswz;
      const int o1 = (((2*ks+1)*64) | (g4*16)) ^ aswz;
      short8 s0 = av ? *(const short8*)(abase + o0) : (short8){0,0,0,0,0,0,0,0};
      short8 s1 = av ? *(const short8*)(abase + o1) : (short8){0,0,0,0,0,0,0,0};
      a0 = __builtin_amdgcn_mfma_f32_16x16x32_bf16(s0, wf[2*ks  ], a0, 0, 0, 0);
      a1 = __builtin_amdgcn_mfma_f32_16x16x32_bf16(s1, wf[2*ks+1], a1, 0, 0, 0);
    }

    // exchange i/f/g/o within wave (wave-local LDS: no block barrier needed)
    if (g4 < 2){
#pragma unroll
      for (int q = 0; q < 4; ++q)
        ex[wv][(jl*4 + gate)*8 + (g4*4 + q)] = a0[q] + a1[q] + xgv[q];
    }

    if (l < 32){
      const float iv = ex[wv][(ujl*4 + 0)*8 + ub];
      const float fv = ex[wv][(ujl*4 + 1)*8 + ub];
      const float gv = ex[wv][(ujl*4 + 2)*8 + ub];
      const float ov = ex[wv][(ujl*4 + 3)*8 + ub];
      c_reg = fsig(fv)*c_reg + fsig(iv)*ftanh(gv);
      const float h = fsig(ov)*ftanh(c_reg);
      exh[wv][ub*4 + ujl] = f2bf(h);
    }
    // packed 8B INVERTED h store: lane b<8 stores wave's 4 units for batch b
    // (fire-and-forget; consumers poll for all-u16-nonzero)
    if (l < 8 && sv){
      const ull hv = ~(*(const ull*)&exh[wv][l*4]);
      ull* dst = (ull*)&D.hbuf[(size_t)(l*SS + pos)*D.hstride + D.joff + ubase];
      __hip_atomic_store(dst, hv, __ATOMIC_RELAXED, __HIP_MEMORY_SCOPE_AGENT);
    }

    // prefetch xg for t+1 (latency hides under the next poll)
    float xgn[4] = {0.f,0.f,0.f,0.f};
    if (t+1 < SS && g4 < 2 && jv){
      const int npos = D.rev ? (pos - 1) : (pos + 1);
#pragma unroll
      for (int q = 0; q < 4; ++q)
        xgn[q] = D.xg[(size_t)((g4*4+q)*SS + npos)*GG + n];
    }
#pragma unroll
    for (int q = 0; q < 4; ++q) xgv[q] = xgn[q];
  }
}

// --------------------------------------------------------------- final ------
__global__ void kfinal(const unsigned short* __restrict__ hw1,
                       const unsigned short* __restrict__ hpf1,
                       const float* __restrict__ xgr1,
                       const float* __restrict__ w1, const float* __restrict__ b1,
                       const float* __restrict__ w2, const float* __restrict__ b2,
                       const float* __restrict__ wc, const float* __restrict__ bc,
                       float* __restrict__ out){
  __shared__ float red[256];
  const int tid = threadIdx.x;
  for (int b = 0; b < BB; ++b){
    const size_t r = (size_t)(b*SS + (SS-1));
    float ps = 0.f, wsm = 0.f;
    for (int j = tid; j < HH; j += 256){
      // h buffers hold inverted bf16 -> decode (x ? ~x : 0)
      unsigned short hp = hpf1[r*1024 + j];
      unsigned short hw = hw1 [r*1024 + j];
      hp = hp ? (unsigned short)~hp : (unsigned short)0;
      hw = hw ? (unsigned short)~hw : (unsigned short)0;
      ps  += bf2f(hp) * w2[j];
      // para reverse layer-1, step 0 (h0=c0=0): closed form from xg
      const float iv = xgr1[r*GG + j];
      const float gv = xgr1[r*GG + 2000 + j];
      const float ov = xgr1[r*GG + 3000 + j];
      const float cc = sigf(iv)*tanhf(gv);
      ps  += sigf(ov)*tanhf(cc) * w2[HH + j];
      wsm += bf2f(hw) * w1[j];
    }
    red[tid] = ps; __syncthreads();
    for (int s = 128; s > 0; s >>= 1){ if (tid < s) red[tid] += red[tid+s]; __syncthreads(); }
    const float PS = red[0]; __syncthreads();
    red[tid] = wsm; __syncthreads();
    for (int s = 128; s > 0; s >>= 1){ if (tid < s) red[tid] += red[tid+s]; __syncthreads(); }
    const float WS = red[0]; __syncthreads();
    if (tid == 0)
      out[b] = wc[0]*(PS + b2[0]) + wc[1]*(WS + b1[0]) + bc[0];
    __syncthreads();
  }
}

// --------------------------------------------------------------- host -------
extern "C" void kernel_launch(void* const* d_in, const int* in_sizes, int n_in,
                              void* d_out, int out_size, void* d_ws, size_t ws_size,
                              hipStream_t stream){
  const int*   x      = (const int*)  d_in[0];
  const float* embw   = (const float*)d_in[1];
  const float* embp   = (const float*)d_in[2];
  const float* l1Wih0 = (const float*)d_in[3];
  const float* l1Whh0 = (const float*)d_in[4];
  const float* l1b0   = (const float*)d_in[5];
  const float* l1Wih1 = (const float*)d_in[6];
  const float* l1Whh1 = (const float*)d_in[7];
  const float* l1b1   = (const float*)d_in[8];
  const float* f0Wih  = (const float*)d_in[9];
  const float* f0Whh  = (const float*)d_in[10];
  const float* f0b    = (const float*)d_in[11];
  const float* r0Wih  = (const float*)d_in[12];
  const float* r0Whh  = (const float*)d_in[13];
  const float* r0b    = (const float*)d_in[14];
  const float* f1Wih  = (const float*)d_in[15];
  const float* f1Whh  = (const float*)d_in[16];
  const float* f1b    = (const float*)d_in[17];
  const float* r1Wih  = (const float*)d_in[18];
  const float* r1Whh  = (const float*)d_in[19];
  const float* r1b    = (const float*)d_in[20];
  const float* w1     = (const float*)d_in[21];
  const float* b1     = (const float*)d_in[22];
  const float* w2     = (const float*)d_in[23];
  const float* b2     = (const float*)d_in[24];
  const float* wc     = (const float*)d_in[25];
  const float* bc     = (const float*)d_in[26];
  float* out = (float*)d_out;
  (void)in_sizes; (void)n_in; (void)out_size; (void)ws_size;
  (void)r1Whh;

  char* ws = (char*)d_ws;
  size_t off = 0;
  auto alloc = [&](size_t bytes)->char*{
    char* p = ws + off;
    off += (bytes + 255) & ~(size_t)255;
    return p;
  };
  // padded bf16 Wih copies [4096][Kpad]  (r1Wih not needed -- kxg8 reads f32)
  unsigned short* pw_l1Wih0 = (unsigned short*)alloc((size_t)NP*512*2);
  unsigned short* pw_f0Wih  = (unsigned short*)alloc((size_t)NP*768*2);
  unsigned short* pw_r0Wih  = (unsigned short*)alloc((size_t)NP*768*2);
  unsigned short* pw_l1Wih1 = (unsigned short*)alloc((size_t)NP*1024*2);
  unsigned short* pw_f1Wih  = (unsigned short*)alloc((size_t)NP*2048*2);
  // gathered embeddings (bf16)
  unsigned short* a_w = (unsigned short*)alloc((size_t)MM*512*2);
  unsigned short* a_p = (unsigned short*)alloc((size_t)MM*768*2);
  // gate pre-activations (f32), reused across the two layers
  float* xg0 = (float*)alloc((size_t)MM*GG*4);
  float* xg1 = (float*)alloc((size_t)MM*GG*4);
  float* xg2 = (float*)alloc((size_t)MM*GG*4);
  // h sequence buffers (inverted bf16) -- contiguous, zeroed per call
  char* zbase = ws + off;
  unsigned short* h_w0  = (unsigned short*)alloc((size_t)MM*1024*2);
  unsigned short* cat0  = (unsigned short*)alloc((size_t)MM*2048*2); // [fwd|rev|pad]
  unsigned short* h_w1  = (unsigned short*)alloc((size_t)MM*1024*2);
  unsigned short* h_pf1 = (unsigned short*)alloc((size_t)MM*1024*2);
  size_t zwords = (size_t)((ws + off) - zbase) / 4;

  kzero<<<dim3(1024), dim3(256), 0, stream>>>((unsigned int*)zbase, zwords);
  kpadw<<<dim3(1024), dim3(256), 0, stream>>>(l1Wih0, pw_l1Wih0, 512, 512);
  kpadw<<<dim3(1024), dim3(256), 0, stream>>>(f0Wih,  pw_f0Wih,  768, 768);
  kpadw<<<dim3(1024), dim3(256), 0, stream>>>(r0Wih,  pw_r0Wih,  768, 768);
  kpadw<<<dim3(1024), dim3(256), 0, stream>>>(l1Wih1, pw_l1Wih1, 1000, 1024);
  kpadw<<<dim3(1024), dim3(256), 0, stream>>>(f1Wih,  pw_f1Wih,  2000, 2048);
  kgather<<<dim3(512), dim3(256), 0, stream>>>(embw, x, a_w, 512);
  kgather<<<dim3(512), dim3(256), 0, stream>>>(embp, x, a_p, 768);

  // layer-0 projections
  kgemm<<<dim3(512), dim3(256), 0, stream>>>(a_w, pw_l1Wih0, l1b0, xg0, 512);
  kgemm<<<dim3(512), dim3(256), 0, stream>>>(a_p, pw_f0Wih,  f0b,  xg1, 768);
  kgemm<<<dim3(512), dim3(256), 0, stream>>>(a_p, pw_r0Wih,  r0b,  xg2, 768);

  // layer-0 scans: word fwd, para fwd, para rev (rev writes cat0 cols 1000..)
  {
    ScanArgs sa;
    sa.d[0] = LstmDesc{xg0, l1Whh0, h_w0, 1024, 0, 0};
    sa.d[1] = LstmDesc{xg1, f0Whh,  cat0, 2048, 0, 0};
    sa.d[2] = LstmDesc{xg2, r0Whh,  cat0, 2048, 1000, 1};
    kscan<<<dim3(96), dim3(512), 0, stream>>>(sa);
  }

  // decode inverted h (h_w0 + cat0 are contiguous) before layer-1 GEMMs
  kdecode<<<dim3(2048), dim3(256), 0, stream>>>(
      (ull*)h_w0, ((size_t)MM*1024 + (size_t)MM*2048) / 4);

  // layer-1 projections (A = layer-0 h sequences, decoded)
  kgemm<<<dim3(512), dim3(256), 0, stream>>>(h_w0, pw_l1Wih1, l1b1, xg0, 1024);
  kgemm<<<dim3(512), dim3(256), 0, stream>>>(cat0, pw_f1Wih,  f1b,  xg1, 2048);
  // para-rev layer-1: only 8 rows (positions b*SS+255) are ever read ->
  // compute them directly (replaces a full 33.6-GFLOP GEMM + weight pad).
  kxg8<<<dim3(1000), dim3(256), 0, stream>>>(r1Wih, r1b, cat0, xg2);

  // layer-1 scans: word fwd + para fwd (para rev needs only step 0 -> kfinal)
  {
    ScanArgs sa;
    sa.d[0] = LstmDesc{xg0, l1Whh1, h_w1,  1024, 0, 0};
    sa.d[1] = LstmDesc{xg1, f1Whh,  h_pf1, 1024, 0, 0};
    sa.d[2] = LstmDesc{nullptr, nullptr, nullptr, 1024, 0, 0};
    kscan<<<dim3(64), dim3(512), 0, stream>>>(sa);
  }

  kfinal<<<dim3(1), dim3(256), 0, stream>>>(h_w1, h_pf1, xg2,
                                            w1, b1, w2, b2, wc, bc, out);
}